// Round 7
// baseline (169.820 us; speedup 1.0000x reference)
//
#include <hip/hip_runtime.h>
#include <math.h>

#define BB 256
#define NN 512
#define DD 6
#define F_IN 62
#define HH 128
#define ND 7
#define TOTAL (BB*NN)   // 131072
#define OPB 640         // padded order slots per batch
#define GPB 40          // 16-row groups per batch
#define TPB 10          // max 64-row tiles per batch

typedef __bf16 bf16x8 __attribute__((ext_vector_type(8)));
typedef float f32x4 __attribute__((ext_vector_type(4)));

__device__ __forceinline__ unsigned short f2bf(float f) {
    unsigned u = __builtin_bit_cast(unsigned, f);
    u = (u + 0x7FFFu + ((u >> 16) & 1u)) >> 16;
    return (unsigned short)u;
}
__device__ __forceinline__ float lo2f(unsigned x) { return __builtin_bit_cast(float, x << 16); }
__device__ __forceinline__ float hi2f(unsigned x) { return __builtin_bit_cast(float, x & 0xFFFF0000u); }

// ---------------- per-batch counting sort by degree, buckets padded to 16 ----------------

__global__ __launch_bounds__(512) void k_sort16(const int* __restrict__ e,
                                                int* __restrict__ order,
                                                int* __restrict__ dgrp,
                                                int* __restrict__ ntiles) {
    __shared__ unsigned int scnt[ND];
    __shared__ unsigned int sbase[ND + 1];
    const int b = blockIdx.x;
    const int t = threadIdx.x;
    if (t < ND) scnt[t] = 0u;
    for (int i = t; i < OPB; i += 512) order[b * OPB + i] = -1;
    __syncthreads();
    int d = 0;
#pragma unroll
    for (int j = 0; j < DD; ++j) d += (e[(b * NN + t) * DD + j] >= 0) ? 1 : 0;
    unsigned rk = atomicAdd(&scnt[d], 1u);
    __syncthreads();
    if (t == 0) {
        unsigned acc = 0;
        for (int k = 0; k < ND; ++k) { sbase[k] = acc; acc += (scnt[k] + 15u) & ~15u; }
        sbase[ND] = acc;
        for (int k = 0; k < ND; ++k)
            for (unsigned g = sbase[k] >> 4; g < (sbase[k + 1] >> 4); ++g)
                dgrp[b * GPB + g] = k;
        for (unsigned g = acc >> 4; g < GPB; ++g) dgrp[b * GPB + g] = 0;
        ntiles[b] = (int)((acc + 63u) >> 6);
    }
    __syncthreads();
    order[b * OPB + sbase[d] + rk] = t;
}

// ---------------- prep: a (f32 [TOTAL][62]) -> bf16 [TOTAL][64], zero-pad ----------------

__global__ __launch_bounds__(256) void k_prep_a(const float* __restrict__ a,
                                                unsigned short* __restrict__ Ap) {
    int u = blockIdx.x * 256 + threadIdx.x;   // unit = 8 cols
    int r = u >> 3;
    int c0 = (u & 7) * 8;
    unsigned short h[8];
#pragma unroll
    for (int i = 0; i < 8; ++i) {
        int c = c0 + i;
        h[i] = (c < F_IN) ? f2bf(a[(size_t)r * F_IN + c]) : (unsigned short)0;
    }
    uint4 p;
    p.x = (unsigned)h[0] | ((unsigned)h[1] << 16);
    p.y = (unsigned)h[2] | ((unsigned)h[3] << 16);
    p.z = (unsigned)h[4] | ((unsigned)h[5] << 16);
    p.w = (unsigned)h[6] | ((unsigned)h[7] << 16);
    *(uint4*)&Ap[(size_t)r * 64 + c0] = p;
}

// ---------------- prep: W [ND][F][HH] f32 -> WT [ND][HH][K] bf16 (K-contig, pad) ----------------

__global__ void k_prep_wt(const float* __restrict__ W, unsigned short* __restrict__ WT,
                          int F, int K) {
    int n = blockIdx.x;   // 0..127
    int d = blockIdx.y;   // 0..6
    for (int k = threadIdx.x; k < K; k += 64) {
        float v = (k < F) ? W[((size_t)d * F + k) * HH + n] : 0.f;
        WT[((size_t)d * HH + n) * K + k] = f2bf(v);
    }
}

// ---------------- conv via MFMA, 16-row degree-pure groups, 1 gather unit / thread ----------------
// Xp: bf16 [TOTAL][K], WT: bf16 [ND][HH][K], Y: bf16 [TOTAL][HH]
// conv1: KB=8, THREADS=512 (8 waves). conv2: KB=16, THREADS=1024 (16 waves).

template<int KB, int THREADS>
__global__ __launch_bounds__(THREADS, 8)
void k_conv_mfma(const unsigned short* __restrict__ Xp,
                 const int* __restrict__ e,
                 const unsigned short* __restrict__ WT,
                 const float* __restrict__ bias,
                 const int* __restrict__ order,
                 const int* __restrict__ dgrp,
                 const int* __restrict__ ntiles,
                 unsigned short* __restrict__ Y) {
    constexpr int K = KB * 8;
    constexpr int LOGKB = (KB == 16) ? 4 : 3;
    constexpr int WAVES = THREADS / 64;
    constexpr int SUBW = WAVES / 4;            // column splits: 2 or 4
    constexpr int CPW = 128 / SUBW;            // cols per wave: 64 or 32
    constexpr int NFR = CPW / 16;              // 16-col fragments per wave: 4 or 2
    __shared__ unsigned short sP[64 * 128];    // gather tile (swizzled) / epilogue staging
    __shared__ int vT[64];
    __shared__ int eT[64 * DD];

    const int t = threadIdx.x;
    const int l = t & 63;
    const int w = t >> 6;

    // XCD-aware mapping: all tiles of a batch on one XCD.
    const int bi = blockIdx.x;
    const int x8 = bi & 7;
    const int j = bi >> 3;
    const int batch = x8 + 8 * (j / TPB);
    const int tile = j % TPB;
    if (tile >= ntiles[batch]) return;

    if (t < 64) vT[t] = order[batch * OPB + tile * 64 + t];
    __syncthreads();
    if (t < 64 * DD) {
        int v = vT[t / DD];
        eT[t] = (v >= 0) ? e[((size_t)batch * NN + v) * DD + (t % DD)] : -1;
    }
    __syncthreads();

    // phase 1: gather-sum, exactly one 8-col unit per thread (max loads in flight)
    {
        const int kb = t & (KB - 1);
        const int n = t >> LOGKB;
        const int v = vT[n];
        float s[8] = {0.f, 0.f, 0.f, 0.f, 0.f, 0.f, 0.f, 0.f};
        if (v >= 0) {
            const unsigned short* base = Xp + (size_t)batch * NN * K + kb * 8;
            uint4 p = *(const uint4*)(base + (size_t)v * K);
            s[0] = lo2f(p.x); s[1] = hi2f(p.x); s[2] = lo2f(p.y); s[3] = hi2f(p.y);
            s[4] = lo2f(p.z); s[5] = hi2f(p.z); s[6] = lo2f(p.w); s[7] = hi2f(p.w);
#pragma unroll
            for (int jj = 0; jj < DD; ++jj) {
                int idx = eT[n * DD + jj];
                if (idx >= 0) {
                    uint4 q = *(const uint4*)(base + (size_t)idx * K);
                    s[0] += lo2f(q.x); s[1] += hi2f(q.x); s[2] += lo2f(q.y); s[3] += hi2f(q.y);
                    s[4] += lo2f(q.z); s[5] += hi2f(q.z); s[6] += lo2f(q.w); s[7] += hi2f(q.w);
                }
            }
        }
        uint4 r;
        r.x = (unsigned)f2bf(s[0]) | ((unsigned)f2bf(s[1]) << 16);
        r.y = (unsigned)f2bf(s[2]) | ((unsigned)f2bf(s[3]) << 16);
        r.z = (unsigned)f2bf(s[4]) | ((unsigned)f2bf(s[5]) << 16);
        r.w = (unsigned)f2bf(s[6]) | ((unsigned)f2bf(s[7]) << 16);
        *(uint4*)&sP[(n * KB + (kb ^ (n & 7))) * 8] = r;
    }
    __syncthreads();

    // phase 2: MFMA — wave w: 16-row group mb (degree-pure), cols [col0, col0+CPW)
    const int lr = l & 15;
    const int lq = l >> 4;
    const int mb = w / SUBW;
    const int col0 = (w % SUBW) * CPW;
    const int d = dgrp[batch * GPB + tile * 4 + mb];
    const int nrow = mb * 16 + lr;

    bf16x8 af[K / 32];
#pragma unroll
    for (int kk = 0; kk < K / 32; ++kk)
        af[kk] = *(const bf16x8*)&sP[(nrow * KB + ((kk * 4 + lq) ^ (nrow & 7))) * 8];

    f32x4 acc[NFR];
#pragma unroll
    for (int fr = 0; fr < NFR; ++fr) { f32x4 z = {0.f, 0.f, 0.f, 0.f}; acc[fr] = z; }
#pragma unroll
    for (int fr = 0; fr < NFR; ++fr) {
        const unsigned short* wp = WT + ((size_t)d * HH + col0 + fr * 16 + lr) * K + lq * 8;
#pragma unroll
        for (int kk = 0; kk < K / 32; ++kk) {
            bf16x8 bfr = *(const bf16x8*)(wp + kk * 32);
            acc[fr] = __builtin_amdgcn_mfma_f32_16x16x32_bf16(af[kk], bfr, acc[fr], 0, 0, 0);
        }
    }

    __syncthreads();   // all A-frag reads done; reuse sP as [64][128] staging
#pragma unroll
    for (int fr = 0; fr < NFR; ++fr) {
        const int col = col0 + fr * 16 + lr;
        const float bv = bias[d * HH + col];
#pragma unroll
        for (int r = 0; r < 4; ++r) {
            const int n = mb * 16 + lq * 4 + r;
            float z = 1.f / (1.f + __expf(-(acc[fr][r] + bv)));
            sP[n * HH + col] = f2bf(z);
        }
    }
    __syncthreads();
    for (int u = t; u < 1024; u += THREADS) {
        int n = u >> 4;
        int c8 = (u & 15) * 8;
        int v = vT[n];
        if (v >= 0) {
            uint4 p = *(const uint4*)&sP[n * HH + c8];
            *(uint4*)&Y[((size_t)batch * NN + v) * HH + c8] = p;
        }
    }
}

// ---------------- pool: P[v] = max(X[v], X[neighbors]) on bf16 rows ----------------
// Grid = 8192 = 32 blocks x 256 batches, XCD-swizzled.

__global__ __launch_bounds__(256) void k_pool_bf(const unsigned short* __restrict__ X,
                                                 const int* __restrict__ e,
                                                 unsigned short* __restrict__ P) {
    const int t = threadIdx.x;
    const int bi = blockIdx.x;
    const int x8 = bi & 7;
    const int j = bi >> 3;
    const int batch = x8 + 8 * (j >> 5);
    const int sub = j & 31;
    const int u = batch * NN + sub * 16 + (t >> 4);
    const int c8 = (t & 15) * 8;
    const int nbase = u & ~(NN - 1);
    float m[8];
    {
        uint4 p = *(const uint4*)(X + (size_t)u * HH + c8);
        m[0] = lo2f(p.x); m[1] = hi2f(p.x); m[2] = lo2f(p.y); m[3] = hi2f(p.y);
        m[4] = lo2f(p.z); m[5] = hi2f(p.z); m[6] = lo2f(p.w); m[7] = hi2f(p.w);
    }
#pragma unroll
    for (int jj = 0; jj < DD; ++jj) {
        int idx = e[u * DD + jj];
        if (idx >= 0) {
            uint4 p = *(const uint4*)(X + (size_t)(nbase + idx) * HH + c8);
            m[0] = fmaxf(m[0], lo2f(p.x)); m[1] = fmaxf(m[1], hi2f(p.x));
            m[2] = fmaxf(m[2], lo2f(p.y)); m[3] = fmaxf(m[3], hi2f(p.y));
            m[4] = fmaxf(m[4], lo2f(p.z)); m[5] = fmaxf(m[5], hi2f(p.z));
            m[6] = fmaxf(m[6], lo2f(p.w)); m[7] = fmaxf(m[7], hi2f(p.w));
        }
    }
    uint4 r;
    r.x = (unsigned)f2bf(m[0]) | ((unsigned)f2bf(m[1]) << 16);
    r.y = (unsigned)f2bf(m[2]) | ((unsigned)f2bf(m[3]) << 16);
    r.z = (unsigned)f2bf(m[4]) | ((unsigned)f2bf(m[5]) << 16);
    r.w = (unsigned)f2bf(m[6]) | ((unsigned)f2bf(m[7]) << 16);
    *(uint4*)&P[(size_t)u * HH + c8] = r;
}

// ---------------- final: pool + partial sum (32 blocks/batch, 1 node/thread-row) ----------------

__global__ __launch_bounds__(256) void k_pool_sum_part(const unsigned short* __restrict__ X,
                                                       const int* __restrict__ e,
                                                       float* __restrict__ partial) {
    __shared__ float red[16][HH + 4];
    const int t = threadIdx.x;
    const int bi = blockIdx.x;
    const int x8 = bi & 7;
    const int j = bi >> 3;
    const int b = x8 + 8 * (j >> 5);
    const int chunk = j & 31;
    const int slot = t >> 4;
    const int c8 = (t & 15) * 8;

    const int u = b * NN + chunk * 16 + slot;
    float m[8];
    {
        uint4 p = *(const uint4*)(X + (size_t)u * HH + c8);
        m[0] = lo2f(p.x); m[1] = hi2f(p.x); m[2] = lo2f(p.y); m[3] = hi2f(p.y);
        m[4] = lo2f(p.z); m[5] = hi2f(p.z); m[6] = lo2f(p.w); m[7] = hi2f(p.w);
    }
#pragma unroll
    for (int jj = 0; jj < DD; ++jj) {
        int idx = e[u * DD + jj];
        if (idx >= 0) {
            uint4 q = *(const uint4*)(X + (size_t)(b * NN + idx) * HH + c8);
            m[0] = fmaxf(m[0], lo2f(q.x)); m[1] = fmaxf(m[1], hi2f(q.x));
            m[2] = fmaxf(m[2], lo2f(q.y)); m[3] = fmaxf(m[3], hi2f(q.y));
            m[4] = fmaxf(m[4], lo2f(q.z)); m[5] = fmaxf(m[5], hi2f(q.z));
            m[6] = fmaxf(m[6], lo2f(q.w)); m[7] = fmaxf(m[7], hi2f(q.w));
        }
    }
#pragma unroll
    for (int i = 0; i < 8; ++i) red[slot][c8 + i] = m[i];
    __syncthreads();
    if (t < HH) {
        float s = 0.f;
#pragma unroll
        for (int k = 0; k < 16; ++k) s += red[k][t];
        partial[((size_t)b * 32 + chunk) * HH + t] = s;
    }
}

// ---------------- final reduce: out[b][c] = sum of 32 partials (deterministic) ----------------

__global__ __launch_bounds__(256) void k_sum_final(const float* __restrict__ partial,
                                                   float* __restrict__ out) {
    int g = blockIdx.x * 256 + threadIdx.x;   // b*HH + c, 32768 total
    int b = g >> 7;
    int c = g & 127;
    float s = 0.f;
#pragma unroll
    for (int k = 0; k < 32; ++k) s += partial[((size_t)b * 32 + k) * HH + c];
    out[g] = s;
}

// ---------------- launcher ----------------

extern "C" void kernel_launch(void* const* d_in, const int* in_sizes, int n_in,
                              void* d_out, int out_size, void* d_ws, size_t ws_size,
                              hipStream_t stream) {
    const float* a  = (const float*)d_in[0];
    const int*   e  = (const int*)d_in[1];
    const float* W0 = (const float*)d_in[2];
    const float* b0 = (const float*)d_in[3];
    const float* W1 = (const float*)d_in[4];
    const float* b1 = (const float*)d_in[5];
    float* out = (float*)d_out;

    char* ws = (char*)d_ws;
    const size_t XB = (size_t)TOTAL * HH * 2;    // 32 MB bf16
    unsigned short* xbuf = (unsigned short*)ws;
    unsigned short* pbuf = (unsigned short*)(ws + XB);
    unsigned short* Ap   = (unsigned short*)(ws + 2 * XB);                 // 16 MB
    float* partial = (float*)Ap;   // reuse: Ap dead after conv1 (4 MB needed)
    unsigned short* WT0  = (unsigned short*)(ws + 2 * XB + (size_t)TOTAL * 64 * 2);
    unsigned short* WT1  = WT0 + (size_t)ND * HH * 64;
    char* ip = (char*)(WT1 + (size_t)ND * HH * 128);
    int* order  = (int*)ip;                          // BB*OPB ints
    int* dgrp   = (int*)(ip + (size_t)BB * OPB * 4); // BB*GPB ints
    int* ntiles = (int*)(ip + (size_t)BB * (OPB + GPB) * 4);

    hipLaunchKernelGGL(k_sort16, dim3(BB), dim3(NN), 0, stream, e, order, dgrp, ntiles);

    hipLaunchKernelGGL(k_prep_a, dim3(TOTAL * 8 / 256), dim3(256), 0, stream, a, Ap);
    hipLaunchKernelGGL(k_prep_wt, dim3(HH, ND), dim3(64), 0, stream, W0, WT0, F_IN, 64);
    hipLaunchKernelGGL(k_prep_wt, dim3(HH, ND), dim3(64), 0, stream, W1, WT1, HH, HH);

    hipLaunchKernelGGL((k_conv_mfma<8, 512>),   dim3(BB * TPB), dim3(512), 0, stream,
                       Ap, e, WT0, b0, order, dgrp, ntiles, xbuf);
    hipLaunchKernelGGL(k_pool_bf, dim3(TOTAL / 16), dim3(256), 0, stream, xbuf, e, pbuf);
    hipLaunchKernelGGL((k_conv_mfma<16, 1024>), dim3(BB * TPB), dim3(1024), 0, stream,
                       pbuf, e, WT1, b1, order, dgrp, ntiles, xbuf);
    hipLaunchKernelGGL(k_pool_sum_part, dim3(BB * 32), dim3(256), 0, stream, xbuf, e, partial);
    hipLaunchKernelGGL(k_sum_final, dim3(BB * HH / 256), dim3(256), 0, stream, partial, out);
}